// Round 9
// baseline (110.411 us; speedup 1.0000x reference)
//
#include <hip/hip_runtime.h>
#include <hip/hip_bf16.h>

// DifferenceOfGaussians on MI355X — round 9: re-anchor on round-7 (last fully
// passing). Round-8 post-mortem: 32-slot window + __launch_bounds__(64,3)
// produced first-launch-correct / replay-wrong output (absmax 508, replays
// self-consistent). No deterministic mechanism found by derivation — change is
// DEAD until explained. This round isolates: round-7 conv kernels verbatim;
// only provably-identical trims (detect runs interior scales only; emit
// synthesizes border-group zeros instead of reading never-written memory).
//
// Standing lessons:
//  - Fused grid barriers on gfx950: ~100us/barrier (rounds 5/6). Do not re-fuse.
//  - fp64 accumulation is the correctness anchor (absmax 0.0). Keep.
//
// Workspace (bytes):
//   OFF_H    : float h[14][640][512]   = 18,350,080  (rows 43..554 = data,
//              rows 0..42 & 555..597 zero guards, 598..639 dead region)
//   OFF_DOG  : float dog[13][512][512] = 13,631,488
//   OFF_BITS : u64  rowbits[6656][8]   =    425,984  (only scales 1..11 written)
//   OFF_GCNT : int  gcnt[832]          (only groups 64..767 written)

#define OFF_H    0
#define OFF_DOG  18350080
#define OFF_BITS 31981568
#define OFF_GCNT 32407552

#define HROWS 640
#define HPAD  43
#define NSIG 13
#define MAXPEAKS 32768

// Build normalized (optionally sign-flipped) weights, zero-padded to 96,
// using one 64-lane wave. Matches reference exp(-(d/(2s))^2) / sum.
__device__ __forceinline__ void make_w(float s, double sgn, double* wl, int lane) {
    int r = (int)(4.0f * s + 0.5f);
    int n = 2 * r + 1;
    double v0 = 0.0, v1 = 0.0;
    double sd = (double)s;
    if (lane < n) {
        double d = (double)(lane - r), q = d / (2.0 * sd);
        v0 = exp(-q * q);
    }
    if (lane + 64 < n) {
        double d = (double)(lane + 64 - r), q = d / (2.0 * sd);
        v1 = exp(-q * q);
    }
    double part = v0 + v1;
    for (int m = 1; m < 64; m <<= 1) part += __shfl_xor(part, m);
    double inv = sgn / part;
    wl[lane] = v0 * inv;
    if (lane + 64 < 96) wl[lane + 64] = v1 * inv;
}

// ---- 1: horizontal blur + guard zeroing; 16 outputs/thread ----
// block 256 = 8 rows x 32 threads; grid (64 rowgroups, 14 planes), heavy first
__global__ __launch_bounds__(256) void hpass(const float* __restrict__ x,
                                             const float* __restrict__ sigma_list,
                                             float* __restrict__ h) {
    const int i = 13 - blockIdx.y;        // heavy plane first
    const int t = threadIdx.x;
    float s = sigma_list[i];
    int r = (int)(4.0f * s + 0.5f);
    int n = 2 * r + 1;
    int nceil = (n + 15) & ~15;

    __shared__ double wl[96];
    if (t < 64) make_w(s, +1.0, wl, t);

    // zero this block's share of the 86 guard rows (64 blocks x 688 = 86*512)
    {
        float* hp = h + i * (HROWS * 512);
        for (int k = t; k < 688; k += 256) {
            int f = blockIdx.x * 688 + k;      // 0..44031
            int g = f >> 9, xc = f & 511;      // g in 0..85
            int row = (g < HPAD) ? g : (g + 512);   // 0..42, 555..597
            hp[row * 512 + xc] = 0.0f;
        }
    }

    // stage 8 zero-padded rows, skewed (addr = p + p/16)
    __shared__ float rowp[8][648];
    int y8 = blockIdx.x * 8;
    for (int rr = 0; rr < 8; ++rr)
        for (int k = t; k < 608; k += 256) {
            int gx = k - 43;
            float val = ((unsigned)gx < 512u) ? x[(y8 + rr) * 512 + gx] : 0.0f;
            rowp[rr][k + (k >> 4)] = val;
        }
    __syncthreads();

    int tsub = t & 31, row = t >> 5;
    int xb = tsub * 16;
    int P0 = 43 - r + xb;
    double acc[16], win[16];
#pragma unroll
    for (int j = 0; j < 16; ++j) acc[j] = 0.0;
#pragma unroll
    for (int sl = 0; sl < 16; ++sl) {
        int p = P0 + sl;
        win[sl] = (double)rowp[row][p + (p >> 4)];
    }
    for (int dc = 0; dc < nceil; dc += 16) {
#pragma unroll
        for (int k = 0; k < 16; ++k) {
            double wd = wl[dc + k];
#pragma unroll
            for (int j = 0; j < 16; ++j)
                acc[j] = fma(wd, win[(k + j) & 15], acc[j]);
            int p = P0 + dc + k + 16;
            win[k] = (double)rowp[row][p + (p >> 4)];
        }
    }
    float* hp = h + (i * HROWS + HPAD + y8 + row) * 512 + xb;
#pragma unroll
    for (int j = 0; j < 16; ++j) hp[j] = (float)acc[j];
}

// Unconditional guarded conv: bp points at padded row (y0 - r + HPAD).
// (round-7 verbatim; W=16 rotating window)
__device__ __forceinline__ void conv_acc(const float* __restrict__ bp,
                                         int nceil, const double* __restrict__ wl,
                                         double (&acc)[16]) {
    double win[16];
#pragma unroll
    for (int sl = 0; sl < 16; ++sl) win[sl] = (double)bp[sl * 512];
    for (int dc = 0; dc < nceil; dc += 16) {
        const float* rp = bp + (dc + 16) * 512;
#pragma unroll
        for (int k = 0; k < 16; ++k) {
            double wd = wl[dc + k];
#pragma unroll
            for (int j = 0; j < 16; ++j)
                acc[j] = fma(wd, win[(k + j) & 15], acc[j]);
            win[k] = (double)rp[k * 512];
        }
    }
}

// ---- 2: vertical blur pair + DoG; 1-wave blocks, heavy plane first ----
// grid (8 x-tiles, 32 y-tiles, 13 planes) = 3328 blocks of 64 threads
__global__ __launch_bounds__(64) void vdog(const float* __restrict__ h,
                                           const float* __restrict__ sigma_list,
                                           float* __restrict__ dog) {
    const int di = 12 - blockIdx.z;
    const int lane = threadIdx.x;
    const int x = blockIdx.x * 64 + lane;
    const int y0 = blockIdx.y * 16;
    float s0 = sigma_list[di], s1 = sigma_list[di + 1];
    int r0 = (int)(4.0f * s0 + 0.5f), n0 = 2 * r0 + 1, nc0 = (n0 + 15) & ~15;
    int r1 = (int)(4.0f * s1 + 0.5f), n1 = 2 * r1 + 1, nc1 = (n1 + 15) & ~15;
    __shared__ double wl0[96], wl1[96];
    make_w(s0, +1.0, wl0, lane);
    make_w(s1, -1.0, wl1, lane);          // negated: acc = conv0 - conv1
    __syncthreads();
    double acc[16];
#pragma unroll
    for (int j = 0; j < 16; ++j) acc[j] = 0.0;
    const float* hp0 = h + di * (HROWS * 512);
    conv_acc(hp0 + (HPAD + y0 - r0) * 512 + x, nc0, wl0, acc);
    const float* hp1 = hp0 + HROWS * 512;
    conv_acc(hp1 + (HPAD + y0 - r1) * 512 + x, nc1, wl1, acc);
    double sg = (double)s0;
    float* dp = dog + (di * 512 + y0) * 512 + x;
#pragma unroll
    for (int j = 0; j < 16; ++j) dp[j * 512] = (float)(acc[j] * sg);
}

// ---- 3: 3x3x3 peak detect; interior scales only (s = 1..11) ----
// grid (64 y-tiles, 11 scales), block 512
__global__ __launch_bounds__(512) void detect(const float* __restrict__ dog,
                                              unsigned long long* __restrict__ rowbits,
                                              int* __restrict__ gcnt) {
    const int s = blockIdx.y + 1;         // 1..11
    const int y0 = blockIdx.x * 8;
    const int group = s * 64 + blockIdx.x;
    const int t = threadIdx.x;
    const int w = t >> 6, lane = t & 63;

    float pm[10], vcen[8];
#pragma unroll
    for (int k = 0; k < 8; ++k) vcen[k] = 0.0f;
#pragma unroll
    for (int q = 0; q < 10; ++q) {
        int yy = y0 - 1 + q;
        float m = -3.0e38f;
        if ((unsigned)yy < 512u) {
            float a = dog[((s - 1) * 512 + yy) * 512 + t];
            float b = dog[(s * 512 + yy) * 512 + t];
            float c = dog[((s + 1) * 512 + yy) * 512 + t];
            m = fmaxf(a, fmaxf(b, c));
            if (q >= 1 && q <= 8) vcen[q - 1] = b;
        }
        pm[q] = m;
    }
    __shared__ float cml[8][512];
    __shared__ int cnt[8][8];
#pragma unroll
    for (int k = 0; k < 8; ++k)
        cml[k][t] = fmaxf(pm[k], fmaxf(pm[k + 1], pm[k + 2]));
    __syncthreads();
#pragma unroll
    for (int k = 0; k < 8; ++k) {
        int y = y0 + k;
        bool peak = false;
        if (t >= 1 && t <= 510 && y >= 1 && y <= 510) {
            float v = vcen[k];
            if (v > 0.001f) {
                float mx = fmaxf(cml[k][t - 1], fmaxf(cml[k][t], cml[k][t + 1]));
                peak = (v >= mx);          // mx includes v
            }
        }
        unsigned long long m = __ballot(peak);
        if (lane == 0) {
            rowbits[(s * 512 + y) * 8 + w] = m;
            cnt[k][w] = __popcll(m);
        }
    }
    __syncthreads();
    if (t == 0) {
        int c = 0;
#pragma unroll
        for (int k = 0; k < 8; ++k)
#pragma unroll
            for (int q = 0; q < 8; ++q) c += cnt[k][q];
        gcnt[group] = c;
    }
}

// ---- 4: ordered emit + padding fill; per-block redundant group reduce ----
// grid 832 blocks x 512 (block b covers scale b/64, rows (b%64)*8 .. +7).
// Border groups (s=0,12) were never written by detect: synthesize zeros, and
// guard every read of rowbits/gcnt for them (stale-poison safety).
__global__ __launch_bounds__(512) void emit(const unsigned long long* __restrict__ rowbits,
                                            const int* __restrict__ gcnt,
                                            const float* __restrict__ sigma_list,
                                            float* __restrict__ out) {
    const int b = blockIdx.x;
    const int s = b >> 6;
    const int y0 = (b & 63) * 8;
    const int t = threadIdx.x;
    const int lane = t & 63;
    const bool interior = (s >= 1 && s <= 11);

    __shared__ unsigned long long m[64];   // [row k][word q]
    __shared__ int pre[64];                // exclusive word prefix (row-major)
    __shared__ int redA[512], redB[512];

    if (interior && t < 64)
        m[t] = rowbits[(s * 512 + y0 + (t >> 3)) * 8 + (t & 7)];

    int pa = 0, pb = 0;
    {
        // groups 0..63 (s=0) and 768..831 (s=12) are border: count as 0,
        // and never load them (memory is stale poison).
        int c0 = (t >= 64) ? gcnt[t] : 0;            // t: 0..511
        int i1 = t + 512;                            // 512..1023
        int c1 = (i1 < 768) ? gcnt[i1] : 0;
        pb = c0 + c1;
        if (t < b) pa += c0;
        if (i1 < b) pa += c1;
    }
    redA[t] = pa;
    redB[t] = pb;
    __syncthreads();
    for (int off = 256; off > 0; off >>= 1) {
        if (t < off) { redA[t] += redA[t + off]; redB[t] += redB[t + off]; }
        __syncthreads();
    }
    int gbase = redA[0];
    int tot = min(redB[0], MAXPEAKS);

    if (interior) {
        if (t < 64) {                      // wave-0 exclusive scan of word counts
            int wc = (int)__popcll(m[t]);
            int inc = wc;
            for (int off = 1; off < 64; off <<= 1) {
                int v = __shfl_up(inc, off);
                if (lane >= off) inc += v;
            }
            pre[t] = inc - wc;
        }
        __syncthreads();

#pragma unroll
        for (int k = 0; k < 8; ++k) {
            int widx = k * 8 + (t >> 6);
            unsigned long long mw = m[widx];
            if ((mw >> lane) & 1ull) {
                int pos = gbase + pre[widx] + (int)__popcll(mw & ((1ull << lane) - 1ull));
                if (pos < MAXPEAKS) {
                    out[pos * 3 + 0] = sigma_list[s];
                    out[pos * 3 + 1] = (float)(y0 + k);
                    out[pos * 3 + 2] = (float)t;
                }
            }
        }
    }

    int idx = b * 512 + t;                 // blocks 0..63 cover all 32768 rows
    if (idx < MAXPEAKS && idx >= tot) {
        out[idx * 3 + 0] = sigma_list[0];
        out[idx * 3 + 1] = 0.0f;
        out[idx * 3 + 2] = 0.0f;
    }
}

extern "C" void kernel_launch(void* const* d_in, const int* in_sizes, int n_in,
                              void* d_out, int out_size, void* d_ws, size_t ws_size,
                              hipStream_t stream) {
    const float* x     = (const float*)d_in[0];   // [1,1,512,512]
    const float* sigma = (const float*)d_in[2];   // [14]
    float* out = (float*)d_out;                   // [32768,3]

    char* ws = (char*)d_ws;
    float* h                     = (float*)(ws + OFF_H);
    float* dog                   = (float*)(ws + OFF_DOG);
    unsigned long long* rowbits  = (unsigned long long*)(ws + OFF_BITS);
    int* gcnt                    = (int*)(ws + OFF_GCNT);

    hpass<<<dim3(64, 14), 256, 0, stream>>>(x, sigma, h);
    vdog<<<dim3(8, 32, 13), 64, 0, stream>>>(h, sigma, dog);
    detect<<<dim3(64, 11), 512, 0, stream>>>(dog, rowbits, gcnt);
    emit<<<832, 512, 0, stream>>>(rowbits, gcnt, sigma, out);
}